// Round 3
// baseline (39393.579 us; speedup 1.0000x reference)
//
#include <hip/hip_runtime.h>

// RNNModel: B=64, T=512, D_IN=256, H=1024, L=3, D_OUT=128 (all fp32)
// R3: ws-adaptive Path A (2x fp32 buf) / B (1 buf + chunked in-place) / C (bf16).
//     recur: 512 thr (2 waves/SIMD), padded LDS strides (<=2-way conflicts),
//     LDS 144.25KiB, 1 block/CU, 256-block cooperative grid.
#define NB   64
#define NT   512
#define DIN  256
#define NH   1024
#define DOUT 128

#define HS_STR 1028   // hs row stride (floats): bank = 4*(b+tk) -> <=2-way
#define WL_STR 20     // Wl row stride (floats): tk-alias broken   -> <=2-way
#define RD_STR 260    // red row stride (floats): 16B-aligned f4, reduce 2-way

typedef float f4 __attribute__((ext_vector_type(4)));
typedef unsigned short bfr;   // raw bf16 storage

__device__ __forceinline__ float b2f(bfr u) {
    union { unsigned u; float f; } v; v.u = ((unsigned)u) << 16; return v.f;
}
__device__ __forceinline__ bfr f2b(float f) {   // round-to-nearest-even
    union { float f; unsigned u; } v; v.f = f;
    unsigned r = v.u + 0x7FFFu + ((v.u >> 16) & 1u);
    return (bfr)(r >> 16);
}

template <typename T> __device__ __forceinline__ f4 load4(const T* p);
template <> __device__ __forceinline__ f4 load4<float>(const float* p) { return *(const f4*)p; }
template <> __device__ __forceinline__ f4 load4<bfr>(const bfr* p) {
    ushort4 u = *(const ushort4*)p;
    f4 r; r[0] = b2f(u.x); r[1] = b2f(u.y); r[2] = b2f(u.z); r[3] = b2f(u.w); return r;
}
template <typename T> __device__ __forceinline__ void store1(T* p, float v);
template <> __device__ __forceinline__ void store1<float>(float* p, float v) { *p = v; }
template <> __device__ __forceinline__ void store1<bfr>(bfr* p, float v) { *p = f2b(v); }
template <typename T> __device__ __forceinline__ float load1(const T* p);
template <> __device__ __forceinline__ float load1<float>(const float* p) { return *p; }
template <> __device__ __forceinline__ float load1<bfr>(const bfr* p) { return b2f(*p); }

// ===================== input projection GEMM =====================
// logical rows r in [0, NB<<LOG2CT); A row addr = (r>>LOG2CT)*NT + tOff + (r&(CT-1))
// (identity when LOG2CT=9, tOff=0). out is compact [rows][NH].
// out[r][n] = sum_k A[r][k]*W[n][k] + bih[n] + bhh[n]
template <int K, int LOG2CT, typename TA, typename TO>
__global__ __launch_bounds__(256)
void proj_kernel(const TA* __restrict__ A, const float* __restrict__ W,
                 const float* __restrict__ bih, const float* __restrict__ bhh,
                 TO* __restrict__ out, int tOff)
{
    __shared__ float As[16][68];   // [k][m], pad 68: 16B-align + conflict-free
    __shared__ float Ws[16][68];   // [k][n]
    const int tid = threadIdx.x;
    const int CTM = (1 << LOG2CT) - 1;
    const int m0 = (blockIdx.x >> 4) << 6;     // grid = (rows/64)*16
    const int n0 = (blockIdx.x & 15) << 6;
    const int tm = tid & 15, tn = tid >> 4;
    const int lr = tid >> 2, lc = tid & 3;

    const int rA = m0 + lr;
    const long mrowA = (long)(rA >> LOG2CT) * NT + tOff + (rA & CTM);

    float acc[4][4] = {};
    for (int k0 = 0; k0 < K; k0 += 16) {
        f4 av = load4<TA>(&A[mrowA * K + k0 + lc * 4]);
        f4 wv = *(const f4*)&W[(n0 + lr) * K + k0 + lc * 4];
        __syncthreads();
        #pragma unroll
        for (int j = 0; j < 4; ++j) {
            As[lc * 4 + j][lr] = av[j];
            Ws[lc * 4 + j][lr] = wv[j];
        }
        __syncthreads();
        #pragma unroll
        for (int k = 0; k < 16; ++k) {
            f4 a = *(const f4*)&As[k][tm * 4];
            f4 w = *(const f4*)&Ws[k][tn * 4];
            #pragma unroll
            for (int i = 0; i < 4; ++i)
                #pragma unroll
                for (int j = 0; j < 4; ++j)
                    acc[i][j] += a[i] * w[j];
        }
    }
    #pragma unroll
    for (int j = 0; j < 4; ++j) {
        const int n = n0 + tn * 4 + j;
        const float bias = bih[n] + bhh[n];
        #pragma unroll
        for (int i = 0; i < 4; ++i)
            store1<TO>(&out[(long)(m0 + tm * 4 + i) * NH + n], acc[i][j] + bias);
    }
}

// ===================== chunk copy-back (compact Q -> strided P rows) ============
template <typename TP, int L2CT>
__global__ __launch_bounds__(256)
void copyback_kernel(const TP* __restrict__ Q, TP* __restrict__ P, int tOff)
{
    const int r = blockIdx.x, tid = threadIdx.x;
    const int b = r >> L2CT, t = r & ((1 << L2CT) - 1);
    const TP* q = Q + (long)r * NH;
    TP* p = P + ((long)b * NT + tOff + t) * NH;
    #pragma unroll
    for (int j = 0; j < 4; ++j) p[tid + j * 256] = q[tid + j * 256];
}

// ===================== recurrent layer (cooperative, 256 WGs x 512 thr) =========
// P[b][t][:] holds pre; in-place: P[:,t,:] <- h_t = relu(pre_t + Whh @ h_{t-1}).
// h mirrored fp32 into Hring[t&1] (compact 256KB/slot) for next-step staging.
// WG tile [16b x 16n]; K split 32-way (tk), 4b x 4n micro; LDS tree-reduce.
// LDS: Wl 80KB + hs 64.25KB = 144.25KiB (red overlays hs).
template <typename TP>
__global__ __launch_bounds__(512, 2)
void recur_kernel(const float* __restrict__ Whh, TP* __restrict__ P,
                  float* __restrict__ Hring, unsigned* __restrict__ sy)
{
    __shared__ float Wl[NH * WL_STR];    // Wl[k*20+r] = Whh[nBase+r][k]  80 KB
    __shared__ float hs[16 * HS_STR];    // hs[b*1028+k]                  64.25 KB
    float* red = hs;                     // overlay: red[tk*260 + b*16+n], 8320 fl

    const int tid   = threadIdx.x;
    const int nBase = (blockIdx.x & 63) << 4;   // 64 n-tiles
    const int bBase = (blockIdx.x >> 6) << 4;   // 4  b-tiles
    const int tb = tid & 3, tn = (tid >> 2) & 3, tk = tid >> 4;  // tk in [0,32)
    const int half = tid >> 8, col = (tid & 255) * 4;            // staging roles
    const int ob = (tid & 255) >> 4, on = tid & 15;              // reduce roles

    // one-time: W tile transposed into LDS (persists all 512 steps)
    #pragma unroll
    for (int r8 = 0; r8 < 8; ++r8) {
        const int r = half * 8 + r8;
        f4 w = *(const f4*)&Whh[(nBase + r) * NH + col];
        #pragma unroll
        for (int j = 0; j < 4; ++j) Wl[(col + j) * WL_STR + r] = w[j];
    }
    for (int i = tid; i < 16 * HS_STR; i += 512) hs[i] = 0.f;   // h_{-1} = 0
    __syncthreads();

    #pragma unroll 1
    for (int ts = 0; ts < NT; ++ts) {
        // ---- partial matvec over this thread's 32-wide k comb ----
        float acc[4][4] = {};
        #pragma unroll
        for (int kk = 0; kk < 8; ++kk) {
            const int kb = kk * 128 + tk * 4;
            f4 hv[4], wv[4];
            #pragma unroll
            for (int i = 0; i < 4; ++i)
                hv[i] = *(const f4*)&hs[(tb * 4 + i) * HS_STR + kb];
            #pragma unroll
            for (int jj = 0; jj < 4; ++jj)
                wv[jj] = *(const f4*)&Wl[(kb + jj) * WL_STR + tn * 4];
            #pragma unroll
            for (int jj = 0; jj < 4; ++jj)
                #pragma unroll
                for (int i = 0; i < 4; ++i)
                    #pragma unroll
                    for (int j = 0; j < 4; ++j)
                        acc[i][j] += hv[i][jj] * wv[jj][j];
        }
        __syncthreads();   // all hs reads done before red overlay write
        #pragma unroll
        for (int i = 0; i < 4; ++i) {
            f4 t; t[0] = acc[i][0]; t[1] = acc[i][1]; t[2] = acc[i][2]; t[3] = acc[i][3];
            *(f4*)&red[tk * RD_STR + (tb * 4 + i) * 16 + tn * 4] = t;
        }
        __syncthreads();

        // ---- reduce 32 partials, add pre, relu, store (threads 0..255) ----
        if (tid < 256) {
            float s = 0.f;
            #pragma unroll
            for (int q = 0; q < 32; ++q) s += red[q * RD_STR + tid];
            TP* pp = &P[((long)(bBase + ob) * NT + ts) * NH + nBase + on];
            const float h = fmaxf(s + load1<TP>(pp), 0.f);
            store1<TP>(pp, h);
            Hring[(ts & 1) * (NB * NH) + (bBase + ob) * NH + nBase + on] = h;
        }
        if (ts == NT - 1) break;

        // ---- grid barrier: release h_t, acquire everyone's h_t ----
        __syncthreads();                 // per-wave vmcnt(0) drain, then barrier
        if (tid == 0) {
            __threadfence();             // agent release
            const unsigned g = (unsigned)blockIdx.x >> 4;   // 16 groups of 16
            unsigned o1 = __hip_atomic_fetch_add(&sy[g * 16], 1u,
                              __ATOMIC_ACQ_REL, __HIP_MEMORY_SCOPE_AGENT);
            if ((o1 & 15u) == 15u) {
                unsigned o2 = __hip_atomic_fetch_add(&sy[256], 1u,
                                  __ATOMIC_ACQ_REL, __HIP_MEMORY_SCOPE_AGENT);
                if ((o2 & 15u) == 15u)
                    __hip_atomic_store(&sy[272], (unsigned)(ts + 1),
                                       __ATOMIC_RELEASE, __HIP_MEMORY_SCOPE_AGENT);
            }
            while (__hip_atomic_load(&sy[272], __ATOMIC_RELAXED,
                                     __HIP_MEMORY_SCOPE_AGENT) < (unsigned)(ts + 1))
                __builtin_amdgcn_s_sleep(2);
            __threadfence();             // agent acquire
        }
        __syncthreads();

        // ---- stage h_t (fp32 compact, own 16-b rows) into LDS ----
        const float* hsrc = Hring + (ts & 1) * (NB * NH);
        #pragma unroll
        for (int r8 = 0; r8 < 8; ++r8) {
            const int r = half * 8 + r8;
            f4 v = *(const f4*)&hsrc[(bBase + r) * NH + col];
            *(f4*)&hs[r * HS_STR + col] = v;
        }
        __syncthreads();
    }
}

// ===================== final FC on last timestep =====================
template <typename TP>
__global__ __launch_bounds__(128)
void fc_kernel(const TP* __restrict__ seq, const float* __restrict__ fcw,
               const float* __restrict__ fcb, float* __restrict__ out)
{
    __shared__ float hrow[NH];
    const int b = blockIdx.x, tid = threadIdx.x;
    for (int i = tid * 4; i < NH; i += 128 * 4) {
        f4 v = load4<TP>(&seq[((long)b * NT + (NT - 1)) * NH + i]);
        *(f4*)&hrow[i] = v;
    }
    __syncthreads();
    float s = 0.f;
    const float* wr = &fcw[tid * NH];
    for (int k = 0; k < NH; k += 4) {
        f4 w = *(const f4*)&wr[k];
        s += w[0] * hrow[k] + w[1] * hrow[k + 1] + w[2] * hrow[k + 2] + w[3] * hrow[k + 3];
    }
    out[b * DOUT + tid] = s + fcb[tid];
}

// ===================== launchers =====================
template <typename TP>
static void coop_recur(const float* W, TP* P, float* Hring, unsigned* sy,
                       hipStream_t stream)
{
    hipMemsetAsync(sy, 0, 4096, stream);
    const float* Wp = W; TP* Pp = P; float* H = Hring; unsigned* s = sy;
    void* args[4] = { &Wp, &Pp, &H, &s };
    hipLaunchCooperativeKernel((const void*)recur_kernel<TP>, dim3(256), dim3(512),
                               args, 0, stream);
}

// Path A: two full fp32 buffers, whole-layer projections
static void run_pathA(const float* x, const float* wih0, const float* wihr,
                      const float* whh, const float* bih, const float* bhh,
                      const float* fcw, const float* fcb, float* out,
                      unsigned* sy, float* Hring, float* P0, float* P1,
                      hipStream_t stream)
{
    const dim3 blk(256);
    proj_kernel<DIN, 9, float, float><<<8192, blk, 0, stream>>>(x, wih0, bih, bhh, P0, 0);
    coop_recur<float>(whh, P0, Hring, sy, stream);
    proj_kernel<NH, 9, float, float><<<8192, blk, 0, stream>>>(P0, wihr,
        bih + NH, bhh + NH, P1, 0);
    coop_recur<float>(whh + NH * NH, P1, Hring, sy, stream);
    proj_kernel<NH, 9, float, float><<<8192, blk, 0, stream>>>(P1, wihr + NH * NH,
        bih + 2 * NH, bhh + 2 * NH, P0, 0);
    coop_recur<float>(whh + 2 * (NH * NH), P0, Hring, sy, stream);
    fc_kernel<float><<<dim3(NB), dim3(128), 0, stream>>>(P0, fcw, fcb, out);
}

// Paths B/C: single buffer, chunked in-place projections for layers 1,2
template <typename TP>
static void run_pathBC(const float* x, const float* wih0, const float* wihr,
                       const float* whh, const float* bih, const float* bhh,
                       const float* fcw, const float* fcb, float* out,
                       unsigned* sy, float* Hring, TP* P, TP* Q, hipStream_t stream)
{
    const dim3 blk(256);
    proj_kernel<DIN, 9, float, TP><<<8192, blk, 0, stream>>>(x, wih0, bih, bhh, P, 0);
    coop_recur<TP>(whh, P, Hring, sy, stream);
    for (int l = 1; l < 3; ++l) {
        const float* wih = wihr + (long)(l - 1) * NH * NH;
        for (int c = 0; c < NT / 32; ++c) {
            proj_kernel<NH, 5, TP, TP><<<512, blk, 0, stream>>>(P, wih, bih + l * NH,
                                                                bhh + l * NH, Q, c * 32);
            copyback_kernel<TP, 5><<<NB * 32, blk, 0, stream>>>(Q, P, c * 32);
        }
        coop_recur<TP>(whh + (long)l * NH * NH, P, Hring, sy, stream);
    }
    fc_kernel<TP><<<dim3(NB), dim3(128), 0, stream>>>(P, fcw, fcb, out);
}

extern "C" void kernel_launch(void* const* d_in, const int* in_sizes, int n_in,
                              void* d_out, int out_size, void* d_ws, size_t ws_size,
                              hipStream_t stream)
{
    (void)in_sizes; (void)n_in; (void)out_size;
    const float* x    = (const float*)d_in[0];
    const float* wih0 = (const float*)d_in[1];
    const float* wihr = (const float*)d_in[2];
    const float* whh  = (const float*)d_in[3];
    const float* bih  = (const float*)d_in[4];
    const float* bhh  = (const float*)d_in[5];
    const float* fcw  = (const float*)d_in[6];
    const float* fcb  = (const float*)d_in[7];
    float* out = (float*)d_out;

    char* ws = (char*)d_ws;
    unsigned* sy = (unsigned*)ws;                         // 4 KB barrier counters
    float* Hring = (float*)(ws + 4096);                   // 2 x 64x1024 fp32 = 512 KB
    char* base = ws + 4096 + 2ull * NB * NH * 4;

    const size_t pF32 = (size_t)NB * NT * NH * 4;         // 128 MiB
    const size_t qF32 = (size_t)NB * 32 * NH * 4;         // 8 MiB
    const size_t head = 4096 + 2ull * NB * NH * 4;
    const size_t needA = head + 2 * pF32;                 // ~256.5 MiB
    const size_t needB = head + pF32 + qF32;              // ~136.5 MiB

    if (ws_size >= needA) {
        float* P0 = (float*)base;
        float* P1 = (float*)(base + pF32);
        run_pathA(x, wih0, wihr, whh, bih, bhh, fcw, fcb, out,
                  sy, Hring, P0, P1, stream);
    } else if (ws_size >= needB) {
        float* P = (float*)base;
        float* Q = (float*)(base + pF32);
        run_pathBC<float>(x, wih0, wihr, whh, bih, bhh, fcw, fcb, out,
                          sy, Hring, P, Q, stream);
    } else {
        bfr* P = (bfr*)base;
        bfr* Q = (bfr*)(base + pF32 / 2);
        run_pathBC<bfr>(x, wih0, wihr, whh, bih, bhh, fcw, fcb, out,
                        sy, Hring, P, Q, stream);
    }
}

// Round 4
// 12287.264 us; speedup vs baseline: 3.2060x; 3.2060x over previous
//
#include <hip/hip_runtime.h>

// RNNModel: B=64, T=512, D_IN=256, H=1024, L=3, D_OUT=128 (all fp32)
// R4: sync rewrite. 4 independent 64-WG batch-groups; flag-per-WG + lane-parallel
//     poll; h via agent-atomic stores + sc0/sc1 asm loads; NO threadfence (no
//     wbl2 / no L2 invalidate -> P stays L2-warm). pre prefetched above matvec.
#define NB   64
#define NT   512
#define DIN  256
#define NH   1024
#define DOUT 128

#define HS_STR 1028   // hs row stride (floats): <=2-way LDS conflicts
#define WL_STR 20     // Wl row stride
#define RD_STR 260    // red row stride

typedef float f4 __attribute__((ext_vector_type(4)));
typedef float f2 __attribute__((ext_vector_type(2)));
typedef unsigned short bfr;   // raw bf16 storage

__device__ __forceinline__ float b2f(bfr u) {
    union { unsigned u; float f; } v; v.u = ((unsigned)u) << 16; return v.f;
}
__device__ __forceinline__ bfr f2b(float f) {   // round-to-nearest-even
    union { float f; unsigned u; } v; v.f = f;
    unsigned r = v.u + 0x7FFFu + ((v.u >> 16) & 1u);
    return (bfr)(r >> 16);
}

template <typename T> __device__ __forceinline__ f4 load4(const T* p);
template <> __device__ __forceinline__ f4 load4<float>(const float* p) { return *(const f4*)p; }
template <> __device__ __forceinline__ f4 load4<bfr>(const bfr* p) {
    ushort4 u = *(const ushort4*)p;
    f4 r; r[0] = b2f(u.x); r[1] = b2f(u.y); r[2] = b2f(u.z); r[3] = b2f(u.w); return r;
}
template <typename T> __device__ __forceinline__ void store1(T* p, float v);
template <> __device__ __forceinline__ void store1<float>(float* p, float v) { *p = v; }
template <> __device__ __forceinline__ void store1<bfr>(bfr* p, float v) { *p = f2b(v); }
template <typename T> __device__ __forceinline__ float load1(const T* p);
template <> __device__ __forceinline__ float load1<float>(const float* p) { return *p; }
template <> __device__ __forceinline__ float load1<bfr>(const bfr* p) { return b2f(*p); }

// ===================== input projection GEMM (unchanged, passed R3) ============
template <int K, int LOG2CT, typename TA, typename TO>
__global__ __launch_bounds__(256)
void proj_kernel(const TA* __restrict__ A, const float* __restrict__ W,
                 const float* __restrict__ bih, const float* __restrict__ bhh,
                 TO* __restrict__ out, int tOff)
{
    __shared__ float As[16][68];
    __shared__ float Ws[16][68];
    const int tid = threadIdx.x;
    const int CTM = (1 << LOG2CT) - 1;
    const int m0 = (blockIdx.x >> 4) << 6;
    const int n0 = (blockIdx.x & 15) << 6;
    const int tm = tid & 15, tn = tid >> 4;
    const int lr = tid >> 2, lc = tid & 3;

    const int rA = m0 + lr;
    const long mrowA = (long)(rA >> LOG2CT) * NT + tOff + (rA & CTM);

    float acc[4][4] = {};
    for (int k0 = 0; k0 < K; k0 += 16) {
        f4 av = load4<TA>(&A[mrowA * K + k0 + lc * 4]);
        f4 wv = *(const f4*)&W[(n0 + lr) * K + k0 + lc * 4];
        __syncthreads();
        #pragma unroll
        for (int j = 0; j < 4; ++j) {
            As[lc * 4 + j][lr] = av[j];
            Ws[lc * 4 + j][lr] = wv[j];
        }
        __syncthreads();
        #pragma unroll
        for (int k = 0; k < 16; ++k) {
            f4 a = *(const f4*)&As[k][tm * 4];
            f4 w = *(const f4*)&Ws[k][tn * 4];
            #pragma unroll
            for (int i = 0; i < 4; ++i)
                #pragma unroll
                for (int j = 0; j < 4; ++j)
                    acc[i][j] += a[i] * w[j];
        }
    }
    #pragma unroll
    for (int j = 0; j < 4; ++j) {
        const int n = n0 + tn * 4 + j;
        const float bias = bih[n] + bhh[n];
        #pragma unroll
        for (int i = 0; i < 4; ++i)
            store1<TO>(&out[(long)(m0 + tm * 4 + i) * NH + n], acc[i][j] + bias);
    }
}

// ===================== chunk copy-back (Paths B/C) =====================
template <typename TP, int L2CT>
__global__ __launch_bounds__(256)
void copyback_kernel(const TP* __restrict__ Q, TP* __restrict__ P, int tOff)
{
    const int r = blockIdx.x, tid = threadIdx.x;
    const int b = r >> L2CT, t = r & ((1 << L2CT) - 1);
    const TP* q = Q + (long)r * NH;
    TP* p = P + ((long)b * NT + tOff + t) * NH;
    #pragma unroll
    for (int j = 0; j < 4; ++j) p[tid + j * 256] = q[tid + j * 256];
}

// ===================== recurrent layer (cooperative, 256 WGs x 512 thr) =========
// 4 independent groups (16 batches each) of 64 WGs; WG tile [16b x 16n].
// Cross-WG h handoff: agent-atomic stores -> flag/WG -> lane-parallel poll ->
// sc0/sc1 asm loads. No threadfence. Hring ping-pong by (ts&1).
template <typename TP>
__global__ __launch_bounds__(512, 2)
void recur_kernel(const float* __restrict__ Whh, TP* __restrict__ P,
                  float* __restrict__ Hring, unsigned* __restrict__ sy)
{
    __shared__ float Wl[NH * WL_STR];    // 80 KB: Wl[k*20+r] = Whh[nBase+r][k]
    __shared__ float hs[16 * HS_STR];    // 64.25 KB: hs[b*1028+k]
    float* red = hs;                     // overlay: red[tk*260 + b*16+n]

    const int tid   = threadIdx.x;
    const int wg    = blockIdx.x;
    const int nBase = (wg & 63) << 4;    // 64 n-tiles
    const int bBase = (wg >> 6) << 4;    // 4 batch-groups of 16
    const int grp   = wg >> 6;
    const int lane  = tid & 63;
    const int tb = tid & 3, tn = (tid >> 2) & 3, tk = tid >> 4;  // tk in [0,32)
    const int half = tid >> 8, col = (tid & 255) * 4;
    const int ob = (tid & 255) >> 4, on = tid & 15;

    // one-time: W tile transposed into LDS
    #pragma unroll
    for (int r8 = 0; r8 < 8; ++r8) {
        const int r = half * 8 + r8;
        f4 w = *(const f4*)&Whh[(nBase + r) * NH + col];
        #pragma unroll
        for (int j = 0; j < 4; ++j) Wl[(col + j) * WL_STR + r] = w[j];
    }
    for (int i = tid; i < 16 * HS_STR; i += 512) hs[i] = 0.f;   // h_{-1}=0
    __syncthreads();

    #pragma unroll 1
    for (int ts = 0; ts < NT; ++ts) {
        // prefetch pre (depends only on ts; written only by this WG this step)
        float pre = 0.f; TP* pp = nullptr;
        if (tid < 256) {
            pp = &P[((long)(bBase + ob) * NT + ts) * NH + nBase + on];
            pre = load1<TP>(pp);
        }

        // ---- partial matvec over this thread's 32-wide k comb ----
        float acc[4][4] = {};
        #pragma unroll
        for (int kk = 0; kk < 8; ++kk) {
            const int kb = kk * 128 + tk * 4;
            f4 hv[4], wv[4];
            #pragma unroll
            for (int i = 0; i < 4; ++i)
                hv[i] = *(const f4*)&hs[(tb * 4 + i) * HS_STR + kb];
            #pragma unroll
            for (int jj = 0; jj < 4; ++jj)
                wv[jj] = *(const f4*)&Wl[(kb + jj) * WL_STR + tn * 4];
            #pragma unroll
            for (int jj = 0; jj < 4; ++jj)
                #pragma unroll
                for (int i = 0; i < 4; ++i)
                    #pragma unroll
                    for (int j = 0; j < 4; ++j)
                        acc[i][j] += hv[i][jj] * wv[jj][j];
        }
        __syncthreads();   // hs reads done before red overlay write
        #pragma unroll
        for (int i = 0; i < 4; ++i) {
            f4 t; t[0] = acc[i][0]; t[1] = acc[i][1]; t[2] = acc[i][2]; t[3] = acc[i][3];
            *(f4*)&red[tk * RD_STR + (tb * 4 + i) * 16 + tn * 4] = t;
        }
        __syncthreads();

        // ---- reduce, relu, publish h ----
        if (tid < 256) {
            float s = 0.f;
            #pragma unroll
            for (int q = 0; q < 32; ++q) s += red[q * RD_STR + tid];
            const float h = fmaxf(s + pre, 0.f);
            store1<TP>(pp, h);                               // cached (layer output)
            __hip_atomic_store(&Hring[(ts & 1) * (NB * NH) + (bBase + ob) * NH + nBase + on],
                               h, __ATOMIC_RELAXED, __HIP_MEMORY_SCOPE_AGENT);
        }
        if (ts == NT - 1) break;

        // ---- publish flag (syncthreads drained every wave's stores) ----
        __syncthreads();
        if (tid == 0)
            __hip_atomic_store(&sy[wg], (unsigned)(ts + 1),
                               __ATOMIC_RELAXED, __HIP_MEMORY_SCOPE_AGENT);

        // ---- lane-parallel poll of this group's 64 flags (every wave) ----
        {
            const unsigned tgt = (unsigned)(ts + 1);
            const unsigned* fp = &sy[grp * 64 + lane];
            unsigned fv = __hip_atomic_load(fp, __ATOMIC_RELAXED, __HIP_MEMORY_SCOPE_AGENT);
            while (!__all((int)(fv >= tgt))) {
                __builtin_amdgcn_s_sleep(1);
                fv = __hip_atomic_load(fp, __ATOMIC_RELAXED, __HIP_MEMORY_SCOPE_AGENT);
            }
        }

        // ---- stage h_t: coherent 8B loads (bypass L1/L2), 16 rows x 8B/thread ----
        {
            const float* hb = Hring + (ts & 1) * (NB * NH) + (long)bBase * NH + (tid << 1);
            f2 stg[16];
            #pragma unroll
            for (int r = 0; r < 16; ++r) {
                const float* a = hb + r * NH;
                asm volatile("global_load_dwordx2 %0, %1, off sc0 sc1"
                             : "=v"(stg[r]) : "v"(a) : "memory");
            }
            asm volatile("s_waitcnt vmcnt(0)" ::: "memory");
            #pragma unroll
            for (int r = 0; r < 16; ++r)
                *(f2*)&hs[r * HS_STR + (tid << 1)] = stg[r];
        }
        __syncthreads();
    }
}

// ===================== final FC on last timestep =====================
template <typename TP>
__global__ __launch_bounds__(128)
void fc_kernel(const TP* __restrict__ seq, const float* __restrict__ fcw,
               const float* __restrict__ fcb, float* __restrict__ out)
{
    __shared__ float hrow[NH];
    const int b = blockIdx.x, tid = threadIdx.x;
    for (int i = tid * 4; i < NH; i += 128 * 4) {
        f4 v = load4<TP>(&seq[((long)b * NT + (NT - 1)) * NH + i]);
        *(f4*)&hrow[i] = v;
    }
    __syncthreads();
    float s = 0.f;
    const float* wr = &fcw[tid * NH];
    for (int k = 0; k < NH; k += 4) {
        f4 w = *(const f4*)&wr[k];
        s += w[0] * hrow[k] + w[1] * hrow[k + 1] + w[2] * hrow[k + 2] + w[3] * hrow[k + 3];
    }
    out[b * DOUT + tid] = s + fcb[tid];
}

// ===================== launchers =====================
template <typename TP>
static void coop_recur(const float* W, TP* P, float* Hring, unsigned* sy,
                       hipStream_t stream)
{
    hipMemsetAsync(sy, 0, 4096, stream);
    const float* Wp = W; TP* Pp = P; float* H = Hring; unsigned* s = sy;
    void* args[4] = { &Wp, &Pp, &H, &s };
    hipLaunchCooperativeKernel((const void*)recur_kernel<TP>, dim3(256), dim3(512),
                               args, 0, stream);
}

static void run_pathA(const float* x, const float* wih0, const float* wihr,
                      const float* whh, const float* bih, const float* bhh,
                      const float* fcw, const float* fcb, float* out,
                      unsigned* sy, float* Hring, float* P0, float* P1,
                      hipStream_t stream)
{
    const dim3 blk(256);
    proj_kernel<DIN, 9, float, float><<<8192, blk, 0, stream>>>(x, wih0, bih, bhh, P0, 0);
    coop_recur<float>(whh, P0, Hring, sy, stream);
    proj_kernel<NH, 9, float, float><<<8192, blk, 0, stream>>>(P0, wihr,
        bih + NH, bhh + NH, P1, 0);
    coop_recur<float>(whh + NH * NH, P1, Hring, sy, stream);
    proj_kernel<NH, 9, float, float><<<8192, blk, 0, stream>>>(P1, wihr + NH * NH,
        bih + 2 * NH, bhh + 2 * NH, P0, 0);
    coop_recur<float>(whh + 2 * (NH * NH), P0, Hring, sy, stream);
    fc_kernel<float><<<dim3(NB), dim3(128), 0, stream>>>(P0, fcw, fcb, out);
}

template <typename TP>
static void run_pathBC(const float* x, const float* wih0, const float* wihr,
                       const float* whh, const float* bih, const float* bhh,
                       const float* fcw, const float* fcb, float* out,
                       unsigned* sy, float* Hring, TP* P, TP* Q, hipStream_t stream)
{
    const dim3 blk(256);
    proj_kernel<DIN, 9, float, TP><<<8192, blk, 0, stream>>>(x, wih0, bih, bhh, P, 0);
    coop_recur<TP>(whh, P, Hring, sy, stream);
    for (int l = 1; l < 3; ++l) {
        const float* wih = wihr + (long)(l - 1) * NH * NH;
        for (int c = 0; c < NT / 32; ++c) {
            proj_kernel<NH, 5, TP, TP><<<512, blk, 0, stream>>>(P, wih, bih + l * NH,
                                                                bhh + l * NH, Q, c * 32);
            copyback_kernel<TP, 5><<<NB * 32, blk, 0, stream>>>(Q, P, c * 32);
        }
        coop_recur<TP>(whh + (long)l * NH * NH, P, Hring, sy, stream);
    }
    fc_kernel<TP><<<dim3(NB), dim3(128), 0, stream>>>(P, fcw, fcb, out);
}

extern "C" void kernel_launch(void* const* d_in, const int* in_sizes, int n_in,
                              void* d_out, int out_size, void* d_ws, size_t ws_size,
                              hipStream_t stream)
{
    (void)in_sizes; (void)n_in; (void)out_size;
    const float* x    = (const float*)d_in[0];
    const float* wih0 = (const float*)d_in[1];
    const float* wihr = (const float*)d_in[2];
    const float* whh  = (const float*)d_in[3];
    const float* bih  = (const float*)d_in[4];
    const float* bhh  = (const float*)d_in[5];
    const float* fcw  = (const float*)d_in[6];
    const float* fcb  = (const float*)d_in[7];
    float* out = (float*)d_out;

    char* ws = (char*)d_ws;
    unsigned* sy = (unsigned*)ws;                         // 4 KB flags
    float* Hring = (float*)(ws + 4096);                   // 2 x 64x1024 fp32
    char* base = ws + 4096 + 2ull * NB * NH * 4;

    const size_t pF32 = (size_t)NB * NT * NH * 4;         // 128 MiB
    const size_t qF32 = (size_t)NB * 32 * NH * 4;         // 8 MiB
    const size_t head = 4096 + 2ull * NB * NH * 4;
    const size_t needA = head + 2 * pF32;                 // ~256.5 MiB
    const size_t needB = head + pF32 + qF32;              // ~136.5 MiB

    if (ws_size >= needA) {
        float* P0 = (float*)base;
        float* P1 = (float*)(base + pF32);
        run_pathA(x, wih0, wihr, whh, bih, bhh, fcw, fcb, out,
                  sy, Hring, P0, P1, stream);
    } else if (ws_size >= needB) {
        float* P = (float*)base;
        float* Q = (float*)(base + pF32);
        run_pathBC<float>(x, wih0, wihr, whh, bih, bhh, fcw, fcb, out,
                          sy, Hring, P, Q, stream);
    } else {
        bfr* P = (bfr*)base;
        bfr* Q = (bfr*)(base + pF32 / 2);
        run_pathBC<bfr>(x, wih0, wihr, whh, bih, bhh, fcw, fcb, out,
                        sy, Hring, P, Q, stream);
    }
}